// Round 14
// baseline (402.360 us; speedup 1.0000x reference)
//
#include <hip/hip_runtime.h>
#include <cstdint>

// Problem constants (B,C,D,H,W) = (4,1,192,192,192)
#define NB    4
#define DD    192
#define HH    192
#define WW    192
#define WPR   6                         // 32-bit words per W-row (192/32)
#define NPB   (DD*HH*WW)                // 7,077,888 voxels per batch
#define NWORDS (NB*DD*HH*WPR)           // 884,736 packed words total
#define NELEM (NB*NPB)                  // 28,311,552 voxels total
#define W_CONN 1e-4f

#define UNROLL 4                        // float4-pairs per thread (all in flight)
#define BLOCKS1 (NELEM / (UNROLL * 1024))  // 6912 blocks, 4096 voxels each
#define BLK_PER_BATCH (NPB / (UNROLL * 1024)) // 1728

// Spread 8 bits (b7..b0) to bit positions 28,24,...,4,0.
__device__ __forceinline__ uint32_t spread4(uint32_t x) {
    x = (x | (x << 12)) & 0x000F000Fu;
    x = (x | (x << 6))  & 0x03030303u;
    x = (x | (x << 3))  & 0x11111111u;
    return x;
}

// log(1 + exp(-|a|)) using hardware v_exp_f32 / v_log_f32 (base-2).
__device__ __forceinline__ float softplus_neg_abs(float a) {
    const float LOG2E = 1.44269504088896340736f;
    const float LN2   = 0.69314718055994530942f;
    float t = __builtin_amdgcn_exp2f(-fabsf(a) * LOG2E);
    return __builtin_amdgcn_logf(1.0f + t) * LN2;
}

// ---------------- Kernel 1: BCE partial sums + pred bit-pack ----------------
// Unchanged from r9/r11 (107 us, 2.12 TB/s useful) — serves as the A side of
// this round's in-situ A/B against k_probe below.
__global__ __launch_bounds__(256) void k_bce_pack(
    const float4* __restrict__ x4, const float4* __restrict__ y4,
    uint32_t* __restrict__ bits, float* __restrict__ bce_sum)
{
    const int  t    = threadIdx.x;
    const int  lane = t & 63;
    const int  wid  = t >> 6;
    const long blockBase = (long)blockIdx.x * (UNROLL * 256);  // float4 units

    float4 xa[UNROLL], ya[UNROLL];
#pragma unroll
    for (int u = 0; u < UNROLL; ++u) {
        const long g = blockBase + (long)u * 256 + t;
        xa[u] = x4[g];
        ya[u] = y4[g];
    }
    __builtin_amdgcn_sched_barrier(0);

    float s = 0.0f;
#pragma unroll
    for (int u = 0; u < UNROLL; ++u) {
        const float4 xv = xa[u];
        const float4 yv = ya[u];
        uint32_t nib = 0;
        {   float xi = xv.x, yi = yv.x;
            s += fmaxf(xi, 0.0f) - xi * yi + softplus_neg_abs(xi);
            nib |= (xi > 0.0f) ? 1u : 0u; }
        {   float xi = xv.y, yi = yv.y;
            s += fmaxf(xi, 0.0f) - xi * yi + softplus_neg_abs(xi);
            nib |= (xi > 0.0f) ? 2u : 0u; }
        {   float xi = xv.z, yi = yv.z;
            s += fmaxf(xi, 0.0f) - xi * yi + softplus_neg_abs(xi);
            nib |= (xi > 0.0f) ? 4u : 0u; }
        {   float xi = xv.w, yi = yv.w;
            s += fmaxf(xi, 0.0f) - xi * yi + softplus_neg_abs(xi);
            nib |= (xi > 0.0f) ? 8u : 0u; }

        const uint64_t b0 = __ballot(nib & 1u);
        const uint64_t b1 = __ballot(nib & 2u);
        const uint64_t b2 = __ballot(nib & 4u);
        const uint64_t b3 = __ballot(nib & 8u);

        const int k = lane & 7;
        uint32_t wrd = spread4((uint32_t)(b0 >> (8 * k)) & 0xFFu)
                     | (spread4((uint32_t)(b1 >> (8 * k)) & 0xFFu) << 1)
                     | (spread4((uint32_t)(b2 >> (8 * k)) & 0xFFu) << 2)
                     | (spread4((uint32_t)(b3 >> (8 * k)) & 0xFFu) << 3);
        if (lane < 8) {
            const long wordBase =
                (blockBase + (long)u * 256 + ((long)wid << 6)) >> 3;
            bits[wordBase + k] = wrd;
        }
    }

    for (int off = 32; off > 0; off >>= 1) s += __shfl_down(s, off);
    __shared__ float red[4];
    if (lane == 0) red[wid] = s;
    __syncthreads();
    if (t == 0) {
        const float tot = red[0] + red[1] + red[2] + red[3];
        const int b = blockIdx.x / BLK_PER_BATCH;      // uniform per block
        atomicAdd(&bce_sum[b], tot);
    }
}

// ---------------- Kernel 2: connectivity via bitwise 26-neighbor OR ---------
__global__ __launch_bounds__(256) void k_conn(
    const uint32_t* __restrict__ bits, unsigned int* __restrict__ conn_cnt)
{
    const int w = blockIdx.x * 256 + threadIdx.x;      // word id < NWORDS
    const int wi  = w % WPR;
    const int t1  = w / WPR;
    const int yy  = t1 % HH;
    const int t2  = t1 / HH;
    const int zz  = t2 % DD;
    const int b   = t2 / DD;

    const int wiL = (wi == 0)       ? (WPR - 1) : (wi - 1);
    const int wiR = (wi == WPR - 1) ? 0         : (wi + 1);

    const uint32_t* __restrict__ bb = bits + (long)b * (DD * HH * WPR);

    uint32_t n26 = 0;
#pragma unroll
    for (int dz = -1; dz <= 1; ++dz) {
#pragma unroll
        for (int dy = -1; dy <= 1; ++dy) {
            int z2 = zz + dz; if (z2 < 0) z2 += DD; if (z2 >= DD) z2 -= DD;
            int y2 = yy + dy; if (y2 < 0) y2 += HH; if (y2 >= HH) y2 -= HH;
            const uint32_t* row = bb + ((long)z2 * HH + y2) * WPR;
            const uint32_t c = row[wi];
            const uint32_t l = row[wiL];
            const uint32_t r = row[wiR];
            uint32_t o = ((c << 1) | (l >> 31)) | ((c >> 1) | (r << 31));
            if (!(dz == 0 && dy == 0)) o |= c;         // center row excludes self
            n26 |= o;
        }
    }
    int cnt = 32 - __popc(n26);                        // voxels passing in word

    for (int off = 32; off > 0; off >>= 1) cnt += __shfl_down(cnt, off);
    __shared__ int red[4];
    const int lane = threadIdx.x & 63;
    const int wid  = threadIdx.x >> 6;
    if (lane == 0) red[wid] = cnt;
    __syncthreads();
    if (threadIdx.x == 0) {
        atomicAdd(&conn_cnt[b], (unsigned int)(red[0] + red[1] + red[2] + red[3]));
    }
}

// ---------------- Kernel 3: final combine -----------------------------------
__global__ void k_final(const float* __restrict__ is_gt,
                        const float* __restrict__ bce_sum,
                        const unsigned int* __restrict__ conn_cnt,
                        float* __restrict__ out)
{
    if (threadIdx.x == 0 && blockIdx.x == 0) {
        const float inv = 1.0f / (float)NPB;
        float loss = 0.0f;
#pragma unroll
        for (int b = 0; b < NB; ++b) {
            loss += is_gt[b] * (bce_sum[b] * inv)
                  + W_CONN  * ((float)conn_cnt[b] * inv);
        }
        out[0] = loss;
    }
}

// ---------------- Probe: in-situ read-BW ceiling measurement ----------------
// Pure float4 read-reduce of the same x,y (226 MB) in m13-copy style:
// grid-stride, 1536 blocks x 256 thr, 18 exact iterations/thread. Result
// goes to a dummy ws sink (never read by k_final). rocprof reports this
// dispatch separately -> measures what THIS machine/context delivers for a
// pure read of this data, separating "k1 structure" from "machine ceiling".
__global__ __launch_bounds__(256) void k_probe(
    const float4* __restrict__ x4, const float4* __restrict__ y4,
    float* __restrict__ sink)
{
    const long stride = (long)gridDim.x * 256;         // 393216 threads
    const long base   = (long)blockIdx.x * 256 + threadIdx.x;
    float4 acc = make_float4(0.f, 0.f, 0.f, 0.f);
#pragma unroll 2
    for (int it = 0; it < 18; ++it) {
        const long i = base + (long)it * stride;
        const float4 a = x4[i];
        const float4 b = y4[i];
        acc.x += a.x + b.x; acc.y += a.y + b.y;
        acc.z += a.z + b.z; acc.w += a.w + b.w;
    }
    float s = acc.x + acc.y + acc.z + acc.w;
    for (int off = 32; off > 0; off >>= 1) s += __shfl_down(s, off);
    if ((threadIdx.x & 63) == 0) atomicAdd(sink, s);
}

extern "C" void kernel_launch(void* const* d_in, const int* in_sizes, int n_in,
                              void* d_out, int out_size, void* d_ws, size_t ws_size,
                              hipStream_t stream) {
    const float* x     = (const float*)d_in[0];
    const float* y     = (const float*)d_in[1];
    const float* is_gt = (const float*)d_in[2];
    float* out = (float*)d_out;

    char* ws = (char*)d_ws;
    float*        bce_sum  = (float*)ws;               // 16 B
    unsigned int* conn_cnt = (unsigned int*)(ws + 64); // 16 B
    float*        sink     = (float*)(ws + 128);       // probe sink (unread)
    uint32_t*     bits     = (uint32_t*)(ws + 256);    // 3.54 MB

    // zero the accumulators (capture-legal)
    hipMemsetAsync(ws, 0, 256, stream);

    k_bce_pack<<<BLOCKS1, 256, 0, stream>>>(
        (const float4*)x, (const float4*)y, bits, bce_sum);
    const int blocks2 = NWORDS / 256;                  // 3456
    k_conn  <<<blocks2, 256, 0, stream>>>(bits, conn_cnt);
    k_final <<<1, 64, 0, stream>>>(is_gt, bce_sum, conn_cnt, out);
    // BW probe last so it cannot perturb the timed kernels' cache state
    // ahead of them; its own dispatch stats come back via rocprof.
    k_probe <<<1536, 256, 0, stream>>>(
        (const float4*)x, (const float4*)y, sink);
}